// Round 4
// baseline (574.949 us; speedup 1.0000x reference)
//
#include <hip/hip_runtime.h>
#include <hip/hip_bf16.h>
#include <stdint.h>

#define BATCH 2
#define NN 32768
#define DIM 512
#define HEADS 8
#define INNER 512
#define G 32
#define M_ROWS (BATCH * NN)   // 65536
#define MAXCHUNK 576
#define NKT 8                 // K tiles of 64 in qkv (512/64)

typedef __attribute__((ext_vector_type(8))) short bf16x8;
typedef __attribute__((ext_vector_type(4))) float floatx4;

__device__ __forceinline__ void gl_lds16(const void* g, void* l) {
    __builtin_amdgcn_global_load_lds(
        (const __attribute__((address_space(1))) uint32_t*)g,
        (__attribute__((address_space(3))) uint32_t*)l, 16, 0, 0);
}

__device__ __forceinline__ short f2bs(float f) {
    __hip_bfloat16 h = __float2bfloat16(f);
    return *reinterpret_cast<short*>(&h);
}

// bijective XCD-chunked remap (nb % 8 == 0): XCD x gets nb/8 consecutive ids
__device__ __forceinline__ int xcd_swizzle(int bid, int nb) {
    return (bid & 7) * (nb >> 3) + (bid >> 3);
}

// swizzled 16B-granule fragment read from a [rows][32] bf16 tile staged by
// gl_lds with pre-swizzled source columns (rule #21: both-sides-or-neither).
__device__ __forceinline__ bf16x8 frag_ld(const char* base, int r, int quad) {
    return *reinterpret_cast<const bf16x8*>(base + r * 64 + ((quad ^ ((r >> 1) & 3)) << 4));
}

// ---------------------------------------------------------------------------
// graph info + chunk table (sorted batch -> binary search; serial chunk build)
// ---------------------------------------------------------------------------
__global__ void graph_info_kernel(const int* __restrict__ batch,
                                  int* __restrict__ starts,
                                  int* __restrict__ sizes,
                                  float* __restrict__ inv,
                                  int* __restrict__ crow0,
                                  int* __restrict__ crows,
                                  int* __restrict__ cbg,
                                  int* __restrict__ cnt) {
    __shared__ int bound[G + 1];
    int g = threadIdx.x;
    if (g <= G) {
        int lo = 0, hi = NN;
        while (lo < hi) { int mid = (lo + hi) >> 1; if (batch[mid] < g) lo = mid + 1; else hi = mid; }
        bound[g] = lo;
    }
    __syncthreads();
    if (g < G) {
        int s0 = bound[g], s1 = bound[g + 1];
        starts[g] = s0;
        int c = s1 - s0;
        sizes[g] = c;
        inv[g] = c ? 1.0f / (float)c : 0.0f;
    }
    if (g == 0) {
        int c = 0;
        for (int b = 0; b < BATCH; b++)
            for (int gg = 0; gg < G; gg++) {
                int s = bound[gg], sz = bound[gg + 1] - s;
                for (int i = 0; i < sz; i += 128) {
                    crow0[c] = b * NN + s + i;
                    crows[c] = min(128, sz - i);
                    cbg[c]   = b * G + gg;
                    c++;
                }
            }
        *cnt = c;
    }
}

// ---------------------------------------------------------------------------
// fp32 -> bf16 convert: one launch covers x, w_qkv, w_out
// ---------------------------------------------------------------------------
__global__ __launch_bounds__(256) void convert3_kernel(
        const float* __restrict__ x, const float* __restrict__ wqkv,
        const float* __restrict__ wout,
        __hip_bfloat16* __restrict__ xb, __hip_bfloat16* __restrict__ wb,
        __hip_bfloat16* __restrict__ wob) {
    int blk = blockIdx.x;
    const float* in;
    __hip_bfloat16* out;
    int i;
    if (blk < 16384)      { in = x;    out = xb;  i = blk * 256 + threadIdx.x; }
    else if (blk < 16768) { in = wqkv; out = wb;  i = (blk - 16384) * 256 + threadIdx.x; }
    else                  { in = wout; out = wob; i = (blk - 16768) * 256 + threadIdx.x; }
    const float4* p = reinterpret_cast<const float4*>(in) + (size_t)i * 2;
    float4 a = p[0], b = p[1];
    __hip_bfloat16 o[8];
    o[0] = __float2bfloat16(a.x); o[1] = __float2bfloat16(a.y);
    o[2] = __float2bfloat16(a.z); o[3] = __float2bfloat16(a.w);
    o[4] = __float2bfloat16(b.x); o[5] = __float2bfloat16(b.y);
    o[6] = __float2bfloat16(b.z); o[7] = __float2bfloat16(b.w);
    *reinterpret_cast<float4*>(out + (size_t)i * 8) = *reinterpret_cast<float4*>(o);
}

// ---------------------------------------------------------------------------
// QKV GEMM, 256x256 tile, 8 waves (2Mx4N), BK=64, 4-phase counted-vmcnt
// pipeline (8-phase-template port). LDS 128 KiB dynamic:
//   A: buf*32K + ksub*16K   (each region [256 rows][32 K] bf16, 64B rows)
//   B: 64K + buf*32K + ksub*16K
// Region stage order per K-tile: {A-k0, B-k0, A-k1, B-k1} = 1 region/phase,
// 2 gl_lds16/thread each. vmcnt(4) at end of phases 1,3 (never 0 mid-loop).
// Epilogue: q scaled direct stores; k/v LN + 256x256 T restage (XOR-swizzled)
// -> transposed [bh][d][n] coalesced stores.
// ---------------------------------------------------------------------------
__global__ __launch_bounds__(512, 2) void qkv_gemm_kernel(
        const __hip_bfloat16* __restrict__ xb, const __hip_bfloat16* __restrict__ wb,
        const float* __restrict__ ln1w, const float* __restrict__ ln1b,
        const float* __restrict__ ln2w, const float* __restrict__ ln2b,
        const float* __restrict__ inv, const int* __restrict__ batch,
        __hip_bfloat16* __restrict__ qn, __hip_bfloat16* __restrict__ kb,
        __hip_bfloat16* __restrict__ vb) {
    extern __shared__ char smem[];          // 131072 bytes
    int bid = xcd_swizzle(blockIdx.y * 6 + blockIdx.x, 6 * 256);
    const int row0 = (bid / 6) * 256;
    const int col0 = (bid % 6) * 256;
    const int t = threadIdx.x;
    const int lane = t & 63;
    const int wave = t >> 6;
    const int wr = wave >> 2;               // 0..1 (M)
    const int wc = wave & 3;                // 0..3 (N)
    const int quad = lane >> 4, lr = lane & 15;

    floatx4 acc[8][4] = {};

    // staging map: thread t covers granules t and t+512 of each 16KB region
    const int srow = t >> 2;                                  // 0..127
    const int scol = (((t & 3) ^ ((t >> 3) & 3))) * 8;        // pre-swizzled col
    const __hip_bfloat16* gA = xb + (size_t)(row0 + srow) * DIM + scol;
    const __hip_bfloat16* gB = wb + (size_t)(col0 + srow) * DIM + scol;

    // prologue: stage all 4 regions of K-tile 0 into buf 0
    #pragma unroll
    for (int r = 0; r < 4; ++r) {
        const int isB = r & 1, ks = r >> 1;
        char* dst = smem + isB * 65536 + ks * 16384 + t * 16;
        const __hip_bfloat16* src = (isB ? gB : gA) + ks * 32;
        gl_lds16(src, dst);
        gl_lds16(src + (size_t)128 * DIM, dst + 8192);
    }
    asm volatile("s_waitcnt vmcnt(4)" ::: "memory");   // regions 0,1 resident
    __builtin_amdgcn_s_barrier();

    for (int kt = 0; kt < NKT; ++kt) {
        const int cb = (kt & 1) << 15;                 // current buf offset
        const int nb = ((kt + 1) & 1) << 15;           // next buf offset
        bf16x8 bfr[4];
        #pragma unroll
        for (int p = 0; p < 4; ++p) {
            const int ks = p >> 1;
            if ((p & 1) == 0) {
                #pragma unroll
                for (int n = 0; n < 4; ++n)
                    bfr[n] = frag_ld(smem + 65536 + cb + ks * 16384,
                                     wc * 64 + n * 16 + lr, quad);
            }
            bf16x8 afr[4];
            #pragma unroll
            for (int i = 0; i < 4; ++i)
                afr[i] = frag_ld(smem + cb + ks * 16384,
                                 wr * 128 + ((p & 1) * 4 + i) * 16 + lr, quad);
            if (kt + 1 < NKT) {                        // stage region p of kt+1
                const int isB = p & 1, ks2 = p >> 1;
                char* dst = smem + isB * 65536 + nb + ks2 * 16384 + t * 16;
                const __hip_bfloat16* src = (isB ? gB : gA) + (kt + 1) * 64 + ks2 * 32;
                gl_lds16(src, dst);
                gl_lds16(src + (size_t)128 * DIM, dst + 8192);
            }
            __builtin_amdgcn_s_barrier();
            asm volatile("s_waitcnt lgkmcnt(0)" ::: "memory");
            __builtin_amdgcn_sched_barrier(0);
            __builtin_amdgcn_s_setprio(1);
            #pragma unroll
            for (int i = 0; i < 4; ++i)
                #pragma unroll
                for (int n = 0; n < 4; ++n)
                    acc[(p & 1) * 4 + i][n] = __builtin_amdgcn_mfma_f32_16x16x32_bf16(
                        afr[i], bfr[n], acc[(p & 1) * 4 + i][n], 0, 0, 0);
            __builtin_amdgcn_s_setprio(0);
            if (p & 1) {                               // end of phases 1, 3
                if (kt < NKT - 1)
                    asm volatile("s_waitcnt vmcnt(4)" ::: "memory");
                else
                    asm volatile("s_waitcnt vmcnt(0)" ::: "memory");
            }
            __builtin_amdgcn_s_barrier();
        }
    }

    const int colw = col0 + wc * 64;
    const int sel = colw >> 9;              // 0=q 1=k 2=v (uniform per block)
    const int hh  = (colw & 511) >> 6;
    const int b_  = row0 >> 15;             // row0 multiple of 256 -> uniform
    const int n0  = row0 & (NN - 1);

    if (sel == 0) {
        #pragma unroll
        for (int m = 0; m < 8; ++m) {
            #pragma unroll
            for (int reg = 0; reg < 4; ++reg) {
                int n = n0 + wr * 128 + m * 16 + quad * 4 + reg;
                float s = inv[batch[n]];
                size_t base = ((size_t)b_ * NN + n) * INNER + hh * 64;
                #pragma unroll
                for (int nf = 0; nf < 4; ++nf)
                    qn[base + nf * 16 + lr] = __float2bfloat16(acc[m][nf][reg] * s);
            }
        }
    } else {
        const float* w  = (sel == 1) ? ln1w : ln2w;
        const float* bb = (sel == 1) ? ln1b : ln2b;
        float lw[4], lb2[4];
        #pragma unroll
        for (int nf = 0; nf < 4; ++nf) { lw[nf] = w[nf * 16 + lr]; lb2[nf] = bb[nf * 16 + lr]; }
        short* T = (short*)smem;            // 256 d x 256 n bf16, granule XOR swz

        #pragma unroll
        for (int m = 0; m < 8; ++m) {
            float f[4][4];                  // [reg][nf]
            #pragma unroll
            for (int reg = 0; reg < 4; ++reg) {
                float v0 = acc[m][0][reg], v1 = acc[m][1][reg],
                      v2 = acc[m][2][reg], v3 = acc[m][3][reg];
                float s = v0 + v1 + v2 + v3;
                s += __shfl_xor(s, 1); s += __shfl_xor(s, 2);
                s += __shfl_xor(s, 4); s += __shfl_xor(s, 8);
                float mu = s * (1.0f / 64.0f);
                float d0 = v0 - mu, d1 = v1 - mu, d2 = v2 - mu, d3 = v3 - mu;
                float s2 = d0 * d0 + d1 * d1 + d2 * d2 + d3 * d3;
                s2 += __shfl_xor(s2, 1); s2 += __shfl_xor(s2, 2);
                s2 += __shfl_xor(s2, 4); s2 += __shfl_xor(s2, 8);
                float rstd = rsqrtf(s2 * (1.0f / 64.0f) + 1e-6f);
                f[reg][0] = d0 * rstd * lw[0] + lb2[0];
                f[reg][1] = d1 * rstd * lw[1] + lb2[1];
                f[reg][2] = d2 * rstd * lw[2] + lb2[2];
                f[reg][3] = d3 * rstd * lw[3] + lb2[3];
            }
            const int nloc0 = wr * 128 + m * 16 + quad * 4;    // 4 consecutive n
            const int glw = nloc0 >> 3, hw = (nloc0 >> 2) & 1;
            #pragma unroll
            for (int nf = 0; nf < 4; ++nf) {
                int dloc = wc * 64 + nf * 16 + lr;
                int gs = glw ^ (dloc & 7);
                short4 pk;
                pk.x = f2bs(f[0][nf]); pk.y = f2bs(f[1][nf]);
                pk.z = f2bs(f[2][nf]); pk.w = f2bs(f[3][nf]);
                *reinterpret_cast<short4*>((char*)T + dloc * 512 + gs * 16 + hw * 8) = pk;
            }
        }
        __syncthreads();
        // store pass: thread t -> d-row t>>1, n-half t&1 (16 x 16B each)
        const int dloc = t >> 1;
        const int j = (col0 & 511) + dloc;                 // 0..511 within k or v
        short* dsts = (short*)((sel == 1) ? kb : vb);
        size_t rowbase = ((size_t)((b_ * HEADS + (j >> 6)) * 64 + (j & 63))) * NN + n0;
        #pragma unroll
        for (int i = 0; i < 16; ++i) {
            int gl = (t & 1) * 16 + i;
            int gs = gl ^ (dloc & 7);
            bf16x8 val = *reinterpret_cast<const bf16x8*>((char*)T + dloc * 512 + gs * 16);
            *reinterpret_cast<bf16x8*>(&dsts[rowbase + gl * 8]) = val;
        }
    }
}

// ---------------------------------------------------------------------------
// Fused ktv + W2: k,v arrive transposed [bh][d][n]; phase 1 has no LDS and no
// barriers (each wave owns stride-128 chunk sequence, 8 vec loads + 16 MFMA
// per 32-node chunk), then one cross-wave fp32 reduction. Phase 3 unchanged.
// ---------------------------------------------------------------------------
__global__ __launch_bounds__(256) void ktv_w2_kernel(
        const short* __restrict__ kt, const short* __restrict__ vt,
        const short* __restrict__ wob,
        const int* __restrict__ starts, const int* __restrict__ sizes,
        short* __restrict__ w2t) {
    __shared__ alignas(16) float red[4][64][68];
    __shared__ alignas(16) short kt_sh[64][72];
    const int bhg = blockIdx.x;
    const int g = bhg & 31;
    const int bh = bhg >> 5;
    const int b = bh >> 3;
    const int h = bh & 7;
    const int s0 = starts[g];
    const int sz = sizes[g];
    const int t = threadIdx.x;
    const int lane = t & 63;
    const int w = t >> 6;
    const int quad = lane >> 4, lr = lane & 15;

    const int n0 = s0 & ~31;
    const int n1 = s0 + sz;
    const size_t base_bh = (size_t)bh * 64 * NN;

    const short* kp[4];
    const short* vp[4];
    #pragma unroll
    for (int mt = 0; mt < 4; mt++) {
        kp[mt] = kt + base_bh + (size_t)(mt * 16 + lr) * NN + quad * 8;
        vp[mt] = vt + base_bh + (size_t)(mt * 16 + lr) * NN + quad * 8;
    }

    floatx4 acc[4][4] = {};
    for (int c = n0 + w * 32; c < n1; c += 128) {
        bf16x8 af[4], bfr[4];
        if (c >= s0 && c + 32 <= n1) {
            #pragma unroll
            for (int mt = 0; mt < 4; mt++) {
                af[mt]  = *reinterpret_cast<const bf16x8*>(kp[mt] + c);
                bfr[mt] = *reinterpret_cast<const bf16x8*>(vp[mt] + c);
            }
        } else {
            #pragma unroll
            for (int mt = 0; mt < 4; mt++)
                #pragma unroll
                for (int j = 0; j < 8; j++) {
                    int n = c + quad * 8 + j;
                    bool ok = (n >= s0) && (n < n1);
                    af[mt][j]  = ok ? kp[mt][c + j] : (short)0;
                    bfr[mt][j] = ok ? vp[mt][c + j] : (short)0;
                }
        }
        #pragma unroll
        for (int mt = 0; mt < 4; mt++)
            #pragma unroll
            for (int et = 0; et < 4; et++)
                acc[mt][et] = __builtin_amdgcn_mfma_f32_16x16x32_bf16(af[mt], bfr[et], acc[mt][et], 0, 0, 0);
    }

    #pragma unroll
    for (int mt = 0; mt < 4; mt++)
        #pragma unroll
        for (int et = 0; et < 4; et++)
            *reinterpret_cast<floatx4*>(&red[w][lane][(mt * 4 + et) * 4]) = acc[mt][et];
    __syncthreads();
    {
        const int mt = w;
        #pragma unroll
        for (int et = 0; et < 4; et++) {
            floatx4 s = *reinterpret_cast<const floatx4*>(&red[0][lane][(mt * 4 + et) * 4]);
            #pragma unroll
            for (int w2 = 1; w2 < 4; w2++)
                s += *reinterpret_cast<const floatx4*>(&red[w2][lane][(mt * 4 + et) * 4]);
            #pragma unroll
            for (int reg = 0; reg < 4; reg++)
                kt_sh[mt * 16 + quad * 4 + reg][et * 16 + lr] = f2bs(s[reg]);
        }
    }
    __syncthreads();

    const short* wsl = wob + h * 64;
    short* w2 = w2t + (size_t)(b * G + g) * 512 * 512 + h * 64;
    bf16x8 b0[4], b1[4];
    #pragma unroll
    for (int dt = 0; dt < 4; dt++) {
        b0[dt] = *reinterpret_cast<const bf16x8*>(&kt_sh[dt * 16 + lr][quad * 8]);
        b1[dt] = *reinterpret_cast<const bf16x8*>(&kt_sh[dt * 16 + lr][quad * 8 + 32]);
    }
    for (int ct = 0; ct < 8; ct++) {
        int c = w * 128 + ct * 16 + lr;
        bf16x8 a0 = *reinterpret_cast<const bf16x8*>(wsl + (size_t)c * INNER + quad * 8);
        bf16x8 a1 = *reinterpret_cast<const bf16x8*>(wsl + (size_t)c * INNER + 32 + quad * 8);
        #pragma unroll
        for (int dt = 0; dt < 4; dt++) {
            floatx4 d = {0.f, 0.f, 0.f, 0.f};
            d = __builtin_amdgcn_mfma_f32_16x16x32_bf16(a0, b0[dt], d, 0, 0, 0);
            d = __builtin_amdgcn_mfma_f32_16x16x32_bf16(a1, b1[dt], d, 0, 0, 0);
            #pragma unroll
            for (int reg = 0; reg < 4; reg++) {
                int crow = w * 128 + ct * 16 + quad * 4 + reg;
                w2[(size_t)crow * 512 + dt * 16 + lr] = f2bs(d[reg]);
            }
        }
    }
}

// ---------------------------------------------------------------------------
// Final segmented GEMM: out[row,:] = qn[row,:] @ W2T[bg]^T + b_out  (fp32 out)
// 2-phase double-buffer + launch_bounds(256,3); XCD-chunked swizzle.
// ---------------------------------------------------------------------------
__global__ __launch_bounds__(256, 3) void final_gemm_kernel(
        const __hip_bfloat16* __restrict__ qn, const __hip_bfloat16* __restrict__ w2t,
        const float* __restrict__ bias,
        const int* __restrict__ crow0, const int* __restrict__ crows,
        const int* __restrict__ cbg, const int* __restrict__ cnt,
        float* __restrict__ out) {
    __shared__ alignas(16) char smem2[32768];   // A0|B0|A1|B1
    int bid = xcd_swizzle(blockIdx.y * 4 + blockIdx.x, 4 * MAXCHUNK);
    const int chunk = bid >> 2;
    if (chunk >= *cnt) return;
    const int row0  = crow0[chunk];
    const int nrows = crows[chunk];
    const int bg    = cbg[chunk];
    const int col0 = (bid & 3) * 128;
    const int t = threadIdx.x;
    const int lane = t & 63;
    const int wave = t >> 6;
    const int wr = wave >> 1, wc = wave & 1;
    const int quad = lane >> 4, lr = lane & 15;

    floatx4 acc[4][4] = {};

    const int srow = t >> 2;
    const int scol = (((t & 3) ^ ((t >> 3) & 3))) * 8;
    const __hip_bfloat16* gA = qn + (size_t)(row0 + srow) * INNER + scol;
    const __hip_bfloat16* gB = w2t + (size_t)bg * 512 * 512 + (size_t)(col0 + srow) * 512 + scol;
    char* lA = smem2 + t * 16;
    char* lB = smem2 + 8192 + t * 16;

    gl_lds16(gA, lA);
    gl_lds16(gA + (size_t)64 * INNER, lA + 4096);
    gl_lds16(gB, lB);
    gl_lds16(gB + (size_t)64 * 512, lB + 4096);
    __syncthreads();

    for (int it = 0; it < INNER / 32; ++it) {
        const int cb = (it & 1) << 14;
        const int nb = cb ^ 16384;
        const int k1 = (it + 1) * 32;
        if (k1 < INNER) {
            gl_lds16(gA + k1, lA + nb);
            gl_lds16(gA + (size_t)64 * INNER + k1, lA + nb + 4096);
            gl_lds16(gB + k1, lB + nb);
            gl_lds16(gB + (size_t)64 * 512 + k1, lB + nb + 4096);
        }
        bf16x8 af[4], bf[4];
        #pragma unroll
        for (int mt = 0; mt < 4; mt++)
            af[mt] = frag_ld(smem2 + cb, wr * 64 + mt * 16 + lr, quad);
        #pragma unroll
        for (int nt = 0; nt < 4; nt++)
            bf[nt] = frag_ld(smem2 + cb + 8192, wc * 64 + nt * 16 + lr, quad);
        #pragma unroll
        for (int mt = 0; mt < 4; mt++)
            #pragma unroll
            for (int nt = 0; nt < 4; nt++)
                acc[mt][nt] = __builtin_amdgcn_mfma_f32_16x16x32_bf16(af[mt], bf[nt], acc[mt][nt], 0, 0, 0);
        __syncthreads();
    }

    #pragma unroll
    for (int nt = 0; nt < 4; nt++) {
        int col = col0 + wc * 64 + nt * 16 + lr;
        float bv = bias[col];
        #pragma unroll
        for (int mt = 0; mt < 4; mt++)
            #pragma unroll
            for (int reg = 0; reg < 4; reg++) {
                int rl = wr * 64 + mt * 16 + quad * 4 + reg;
                if (rl < nrows)
                    out[(size_t)(row0 + rl) * DIM + col] = acc[mt][nt][reg] + bv;
            }
    }
}

// ---------------------------------------------------------------------------
extern "C" void kernel_launch(void* const* d_in, const int* in_sizes, int n_in,
                              void* d_out, int out_size, void* d_ws, size_t ws_size,
                              hipStream_t stream) {
    const float* x     = (const float*)d_in[0];
    const float* w_qkv = (const float*)d_in[1];
    const float* ln1w  = (const float*)d_in[2];
    const float* ln1b  = (const float*)d_in[3];
    const float* ln2w  = (const float*)d_in[4];
    const float* ln2b  = (const float*)d_in[5];
    const float* w_out = (const float*)d_in[6];
    const float* b_out = (const float*)d_in[7];
    const int*   batch = (const int*)d_in[8];
    float* out = (float*)d_out;

    char* ws = (char*)d_ws;
    const size_t MB = 1u << 20;
    __hip_bfloat16* qn  = (__hip_bfloat16*)(ws);              // 64 MiB
    __hip_bfloat16* kb  = (__hip_bfloat16*)(ws + 64 * MB);    // 64 MiB [bh][d][n]
    __hip_bfloat16* vb  = (__hip_bfloat16*)(ws + 128 * MB);   // 64 MiB [bh][d][n]
    __hip_bfloat16* xb  = (__hip_bfloat16*)(ws + 192 * MB);   // xb then w2t
    __hip_bfloat16* w2t = (__hip_bfloat16*)(ws + 192 * MB);
    __hip_bfloat16* wb  = (__hip_bfloat16*)(ws + 256 * MB);   // 1.5 MiB
    __hip_bfloat16* wob = (__hip_bfloat16*)(ws + 258 * MB);   // 0.5 MiB
    char* meta = ws + 259 * MB;
    int*   starts = (int*)(meta);
    int*   sizes  = (int*)(meta + 128);
    float* inv    = (float*)(meta + 256);
    int*   crow0  = (int*)(meta + 512);
    int*   crows  = (int*)(meta + 512 + 4096);
    int*   cbg    = (int*)(meta + 512 + 8192);
    int*   cnt    = (int*)(meta + 512 + 12288);

    static bool attr_set = false;
    if (!attr_set) {
        hipFuncSetAttribute(reinterpret_cast<const void*>(qkv_gemm_kernel),
                            hipFuncAttributeMaxDynamicSharedMemorySize, 131072);
        attr_set = true;
    }

    graph_info_kernel<<<1, 64, 0, stream>>>(batch, starts, sizes, inv,
                                            crow0, crows, cbg, cnt);
    convert3_kernel<<<16896, 256, 0, stream>>>(x, w_qkv, w_out, xb, wb, wob);
    qkv_gemm_kernel<<<dim3(6, M_ROWS / 256), 512, 131072, stream>>>(
        xb, wb, ln1w, ln1b, ln2w, ln2b, inv, batch, qn, kb, vb);
    ktv_w2_kernel<<<BATCH * HEADS * G, 256, 0, stream>>>(
        (const short*)kb, (const short*)vb, (const short*)wob, starts, sizes, (short*)w2t);
    final_gemm_kernel<<<dim3(4, MAXCHUNK), 256, 0, stream>>>(
        qn, w2t, b_out, crow0, crows, cbg, cnt, out);
}

// Round 5
// 534.761 us; speedup vs baseline: 1.0752x; 1.0752x over previous
//
#include <hip/hip_runtime.h>
#include <hip/hip_bf16.h>
#include <stdint.h>

#define BATCH 2
#define NN 32768
#define DIM 512
#define HEADS 8
#define INNER 512
#define G 32
#define M_ROWS (BATCH * NN)   // 65536
#define MAXCHUNK 576

typedef __attribute__((ext_vector_type(8))) short bf16x8;
typedef __attribute__((ext_vector_type(4))) float floatx4;

__device__ __forceinline__ void gl_lds16(const void* g, void* l) {
    __builtin_amdgcn_global_load_lds(
        (const __attribute__((address_space(1))) uint32_t*)g,
        (__attribute__((address_space(3))) uint32_t*)l, 16, 0, 0);
}

__device__ __forceinline__ short f2bs(float f) {
    __hip_bfloat16 h = __float2bfloat16(f);
    return *reinterpret_cast<short*>(&h);
}

// bijective XCD-chunked remap (nb % 8 == 0): XCD x gets nb/8 consecutive ids
__device__ __forceinline__ int xcd_swizzle(int bid, int nb) {
    return (bid & 7) * (nb >> 3) + (bid >> 3);
}

// swizzled 16B-granule fragment read from a [rows][32] bf16 tile staged by
// gl_lds with pre-swizzled source columns (rule #21: both-sides-or-neither).
__device__ __forceinline__ bf16x8 frag_ld(const char* base, int r, int quad) {
    return *reinterpret_cast<const bf16x8*>(base + r * 64 + ((quad ^ ((r >> 1) & 3)) << 4));
}

// ---------------------------------------------------------------------------
// graph info + chunk table. Parallelized: per-graph chunk counts, thread-0
// prefix scan (32 adds), then all 64 (b,g) pairs write chunks concurrently
// (replaces the ~600-iteration serial single-lane loop).
// ---------------------------------------------------------------------------
__global__ void graph_info_kernel(const int* __restrict__ batch,
                                  int* __restrict__ starts,
                                  int* __restrict__ sizes,
                                  float* __restrict__ inv,
                                  int* __restrict__ crow0,
                                  int* __restrict__ crows,
                                  int* __restrict__ cbg,
                                  int* __restrict__ cnt) {
    __shared__ int bound[G + 1];
    __shared__ int pref[G + 1];
    int g = threadIdx.x;
    if (g <= G) {
        int lo = 0, hi = NN;
        while (lo < hi) { int mid = (lo + hi) >> 1; if (batch[mid] < g) lo = mid + 1; else hi = mid; }
        bound[g] = lo;
    }
    __syncthreads();
    if (g < G) {
        int s0 = bound[g], s1 = bound[g + 1];
        starts[g] = s0;
        int c = s1 - s0;
        sizes[g] = c;
        inv[g] = c ? 1.0f / (float)c : 0.0f;
    }
    if (g == 0) {
        int acc = 0;
        for (int gg = 0; gg < G; gg++) {
            pref[gg] = acc;
            acc += (bound[gg + 1] - bound[gg] + 127) >> 7;
        }
        pref[G] = acc;
        *cnt = 2 * acc;
    }
    __syncthreads();
    {
        int b = g >> 5, gg = g & 31;          // g in [0,64)
        int s = bound[gg], sz = bound[gg + 1] - s;
        int base = b * pref[G] + pref[gg];
        int nc = (sz + 127) >> 7;
        for (int i = 0; i < nc; i++) {
            crow0[base + i] = b * NN + s + i * 128;
            crows[base + i] = min(128, sz - i * 128);
            cbg[base + i]   = b * G + gg;
        }
    }
}

// ---------------------------------------------------------------------------
// fp32 -> bf16 convert: one launch covers x, w_qkv, w_out
// ---------------------------------------------------------------------------
__global__ __launch_bounds__(256) void convert3_kernel(
        const float* __restrict__ x, const float* __restrict__ wqkv,
        const float* __restrict__ wout,
        __hip_bfloat16* __restrict__ xb, __hip_bfloat16* __restrict__ wb,
        __hip_bfloat16* __restrict__ wob) {
    int blk = blockIdx.x;
    const float* in;
    __hip_bfloat16* out;
    int i;
    if (blk < 16384)      { in = x;    out = xb;  i = blk * 256 + threadIdx.x; }
    else if (blk < 16768) { in = wqkv; out = wb;  i = (blk - 16384) * 256 + threadIdx.x; }
    else                  { in = wout; out = wob; i = (blk - 16768) * 256 + threadIdx.x; }
    const float4* p = reinterpret_cast<const float4*>(in) + (size_t)i * 2;
    float4 a = p[0], b = p[1];
    __hip_bfloat16 o[8];
    o[0] = __float2bfloat16(a.x); o[1] = __float2bfloat16(a.y);
    o[2] = __float2bfloat16(a.z); o[3] = __float2bfloat16(a.w);
    o[4] = __float2bfloat16(b.x); o[5] = __float2bfloat16(b.y);
    o[6] = __float2bfloat16(b.z); o[7] = __float2bfloat16(b.w);
    *reinterpret_cast<float4*>(out + (size_t)i * 8) = *reinterpret_cast<float4*>(o);
}

// ---------------------------------------------------------------------------
// QKV GEMM (r3-verified structure): 128x128 tile, 2-phase double-buffered
// gl_lds staging, one barrier per K-step, launch_bounds(256,3).
// ---------------------------------------------------------------------------
__global__ __launch_bounds__(256, 3) void qkv_gemm_kernel(
        const __hip_bfloat16* __restrict__ xb, const __hip_bfloat16* __restrict__ wb,
        const float* __restrict__ ln1w, const float* __restrict__ ln1b,
        const float* __restrict__ ln2w, const float* __restrict__ ln2b,
        const float* __restrict__ inv, const int* __restrict__ batch,
        __hip_bfloat16* __restrict__ qn, __hip_bfloat16* __restrict__ kb,
        __hip_bfloat16* __restrict__ vb) {
    // A0 @0 | B0 @8K | A1 @16K | B1 @24K ; reused as T (32K) in epilogue
    __shared__ alignas(16) char smem[32768];
    int bid = xcd_swizzle(blockIdx.y * 12 + blockIdx.x, 12 * 512);
    const int row0 = (bid / 12) * 128;
    const int col0 = (bid % 12) * 128;
    const int t = threadIdx.x;
    const int lane = t & 63;
    const int wave = t >> 6;
    const int wr = wave >> 1, wc = wave & 1;
    const int quad = lane >> 4, lr = lane & 15;

    floatx4 acc[4][4] = {};

    const int srow = t >> 2;
    const int scol = (((t & 3) ^ ((t >> 3) & 3))) * 8;   // pre-swizzled source col
    const __hip_bfloat16* gA = xb + (size_t)(row0 + srow) * DIM + scol;
    const __hip_bfloat16* gB = wb + (size_t)(col0 + srow) * DIM + scol;
    char* lA = smem + t * 16;
    char* lB = smem + 8192 + t * 16;

    // prologue: stage K-step 0 into buffer 0
    gl_lds16(gA, lA);
    gl_lds16(gA + (size_t)64 * DIM, lA + 4096);
    gl_lds16(gB, lB);
    gl_lds16(gB + (size_t)64 * DIM, lB + 4096);
    __syncthreads();

    for (int it = 0; it < DIM / 32; ++it) {
        const int cb = (it & 1) << 14;
        const int nb = cb ^ 16384;
        const int k1 = (it + 1) * 32;
        if (k1 < DIM) {
            gl_lds16(gA + k1, lA + nb);
            gl_lds16(gA + (size_t)64 * DIM + k1, lA + nb + 4096);
            gl_lds16(gB + k1, lB + nb);
            gl_lds16(gB + (size_t)64 * DIM + k1, lB + nb + 4096);
        }
        bf16x8 af[4], bf[4];
        #pragma unroll
        for (int mt = 0; mt < 4; mt++)
            af[mt] = frag_ld(smem + cb, wr * 64 + mt * 16 + lr, quad);
        #pragma unroll
        for (int nt = 0; nt < 4; nt++)
            bf[nt] = frag_ld(smem + cb + 8192, wc * 64 + nt * 16 + lr, quad);
        #pragma unroll
        for (int mt = 0; mt < 4; mt++)
            #pragma unroll
            for (int nt = 0; nt < 4; nt++)
                acc[mt][nt] = __builtin_amdgcn_mfma_f32_16x16x32_bf16(af[mt], bf[nt], acc[mt][nt], 0, 0, 0);
        __syncthreads();
    }

    const int sel = (col0 + wc * 64) >> 9;   // 0=q 1=k 2=v (uniform per block)
    const int hh = ((col0 + wc * 64) & 511) >> 6;

    if (sel == 0) {
        #pragma unroll
        for (int mt = 0; mt < 4; mt++) {
            #pragma unroll
            for (int reg = 0; reg < 4; reg++) {
                int row = row0 + wr * 64 + mt * 16 + quad * 4 + reg;
                int b_ = row >> 15;
                int n = row & (NN - 1);
                float s = inv[batch[n]];
                float v0 = acc[mt][0][reg] * s, v1 = acc[mt][1][reg] * s,
                      v2 = acc[mt][2][reg] * s, v3 = acc[mt][3][reg] * s;
                size_t base = ((size_t)b_ * NN + n) * INNER + hh * 64;
                qn[base + 0 * 16 + lr] = __float2bfloat16(v0);
                qn[base + 1 * 16 + lr] = __float2bfloat16(v1);
                qn[base + 2 * 16 + lr] = __float2bfloat16(v2);
                qn[base + 3 * 16 + lr] = __float2bfloat16(v3);
            }
        }
    } else {
        // ---- k/v: LN, then LDS restage T[d_local][n_local] (swizzled) ----
        const float* w  = (sel == 1) ? ln1w : ln2w;
        const float* bb = (sel == 1) ? ln1b : ln2b;
        float lw[4], lb[4];
        #pragma unroll
        for (int nt = 0; nt < 4; nt++) { lw[nt] = w[nt * 16 + lr]; lb[nt] = bb[nt * 16 + lr]; }
        __hip_bfloat16* dstkv = (sel == 1) ? kb : vb;
        short* T = (short*)smem;           // 128 x 128 bf16, n-granule XOR swizzle

        #pragma unroll
        for (int mt = 0; mt < 4; mt++) {
            float f[4][4];                 // [reg][nt]
            #pragma unroll
            for (int reg = 0; reg < 4; reg++) {
                float v0 = acc[mt][0][reg], v1 = acc[mt][1][reg],
                      v2 = acc[mt][2][reg], v3 = acc[mt][3][reg];
                float s = v0 + v1 + v2 + v3;
                s += __shfl_xor(s, 1); s += __shfl_xor(s, 2);
                s += __shfl_xor(s, 4); s += __shfl_xor(s, 8);
                float mu = s * (1.0f / 64.0f);
                float d0 = v0 - mu, d1 = v1 - mu, d2 = v2 - mu, d3 = v3 - mu;
                float s2 = d0 * d0 + d1 * d1 + d2 * d2 + d3 * d3;
                s2 += __shfl_xor(s2, 1); s2 += __shfl_xor(s2, 2);
                s2 += __shfl_xor(s2, 4); s2 += __shfl_xor(s2, 8);
                float rstd = rsqrtf(s2 * (1.0f / 64.0f) + 1e-6f);
                f[reg][0] = d0 * rstd * lw[0] + lb[0];
                f[reg][1] = d1 * rstd * lw[1] + lb[1];
                f[reg][2] = d2 * rstd * lw[2] + lb[2];
                f[reg][3] = d3 * rstd * lw[3] + lb[3];
            }
            const int c0 = wr * 64 + mt * 16 + quad * 4;   // n_local base
            #pragma unroll
            for (int nt = 0; nt < 4; nt++) {
                int r = wc * 64 + nt * 16 + lr;            // d_local
                int idx = r * 128 + (((c0 >> 3) ^ (r & 15)) << 3) + (c0 & 7);
                short4 pk;
                pk.x = f2bs(f[0][nt]); pk.y = f2bs(f[1][nt]);
                pk.z = f2bs(f[2][nt]); pk.w = f2bs(f[3][nt]);
                *reinterpret_cast<short4*>(&T[idx]) = pk;  // packed ds_write_b64
            }
        }
        __syncthreads();
        const int b_ = row0 >> 15;
        const int n0 = row0 & (NN - 1);
        const int gidx = lane & 15;
        const int rbase = wave * 32 + (lane >> 4) * 8;
        short* dsts = (short*)dstkv;
        #pragma unroll
        for (int i = 0; i < 8; i++) {
            int r = rbase + i;                             // d_local 0..127
            int idx = r * 128 + ((gidx ^ (r & 15)) << 3);
            bf16x8 val = *reinterpret_cast<const bf16x8*>(&T[idx]);
            int j = (col0 & 511) + r;                      // 0..511 within k or v
            size_t addr = ((size_t)((b_ * HEADS + (j >> 6)) * 64 + (j & 63))) * NN
                          + n0 + gidx * 8;
            *reinterpret_cast<bf16x8*>(&dsts[addr]) = val;
        }
    }
}

// ---------------------------------------------------------------------------
// Fused ktv + W2: k,v arrive transposed [bh][d][n]; phase 1 has no LDS and no
// barriers; one cross-wave fp32 reduction. Phase 3 now computes the MFMA with
// SWAPPED operands (D^T): the 4 acc regs land on consecutive d-columns, so
// each (ct,dt) emits ONE packed short4 store (32 stores/thread vs 128 scalar).
// ---------------------------------------------------------------------------
__global__ __launch_bounds__(256) void ktv_w2_kernel(
        const short* __restrict__ kt, const short* __restrict__ vt,
        const short* __restrict__ wob,
        const int* __restrict__ starts, const int* __restrict__ sizes,
        short* __restrict__ w2t) {
    __shared__ alignas(16) float red[4][64][68];
    __shared__ alignas(16) short kt_sh[64][72];
    const int bhg = blockIdx.x;
    const int g = bhg & 31;
    const int bh = bhg >> 5;
    const int b = bh >> 3;
    const int h = bh & 7;
    const int s0 = starts[g];
    const int sz = sizes[g];
    const int t = threadIdx.x;
    const int lane = t & 63;
    const int w = t >> 6;
    const int quad = lane >> 4, lr = lane & 15;

    const int n0 = s0 & ~31;
    const int n1 = s0 + sz;
    const size_t base_bh = (size_t)bh * 64 * NN;

    const short* kp[4];
    const short* vp[4];
    #pragma unroll
    for (int mt = 0; mt < 4; mt++) {
        kp[mt] = kt + base_bh + (size_t)(mt * 16 + lr) * NN + quad * 8;
        vp[mt] = vt + base_bh + (size_t)(mt * 16 + lr) * NN + quad * 8;
    }

    floatx4 acc[4][4] = {};
    for (int c = n0 + w * 32; c < n1; c += 128) {
        bf16x8 af[4], bfr[4];
        if (c >= s0 && c + 32 <= n1) {
            #pragma unroll
            for (int mt = 0; mt < 4; mt++) {
                af[mt]  = *reinterpret_cast<const bf16x8*>(kp[mt] + c);
                bfr[mt] = *reinterpret_cast<const bf16x8*>(vp[mt] + c);
            }
        } else {
            #pragma unroll
            for (int mt = 0; mt < 4; mt++)
                #pragma unroll
                for (int j = 0; j < 8; j++) {
                    int n = c + quad * 8 + j;
                    bool ok = (n >= s0) && (n < n1);
                    af[mt][j]  = ok ? kp[mt][c + j] : (short)0;
                    bfr[mt][j] = ok ? vp[mt][c + j] : (short)0;
                }
        }
        #pragma unroll
        for (int mt = 0; mt < 4; mt++)
            #pragma unroll
            for (int et = 0; et < 4; et++)
                acc[mt][et] = __builtin_amdgcn_mfma_f32_16x16x32_bf16(af[mt], bfr[et], acc[mt][et], 0, 0, 0);
    }

    #pragma unroll
    for (int mt = 0; mt < 4; mt++)
        #pragma unroll
        for (int et = 0; et < 4; et++)
            *reinterpret_cast<floatx4*>(&red[w][lane][(mt * 4 + et) * 4]) = acc[mt][et];
    __syncthreads();
    {
        const int mt = w;
        #pragma unroll
        for (int et = 0; et < 4; et++) {
            floatx4 s = *reinterpret_cast<const floatx4*>(&red[0][lane][(mt * 4 + et) * 4]);
            #pragma unroll
            for (int w2 = 1; w2 < 4; w2++)
                s += *reinterpret_cast<const floatx4*>(&red[w2][lane][(mt * 4 + et) * 4]);
            #pragma unroll
            for (int reg = 0; reg < 4; reg++)
                kt_sh[mt * 16 + quad * 4 + reg][et * 16 + lr] = f2bs(s[reg]);
        }
    }
    __syncthreads();

    // phase 3: W2T rows [w*128, w*128+128), cols h*64..h*64+63.
    // Swapped operands: d = mfma(ktv_frag, w_frag) -> D[dcol][crow] layout:
    //   crow = w*128 + ct*16 + lr    (lane index)
    //   dcol = dt*16 + quad*4 + reg  (reg index -> consecutive cols)
    const short* wsl = wob + h * 64;
    short* w2 = w2t + (size_t)(b * G + g) * 512 * 512 + h * 64;
    bf16x8 b0[4], b1[4];
    #pragma unroll
    for (int dt = 0; dt < 4; dt++) {
        b0[dt] = *reinterpret_cast<const bf16x8*>(&kt_sh[dt * 16 + lr][quad * 8]);
        b1[dt] = *reinterpret_cast<const bf16x8*>(&kt_sh[dt * 16 + lr][quad * 8 + 32]);
    }
    for (int ct = 0; ct < 8; ct++) {
        int c = w * 128 + ct * 16 + lr;
        bf16x8 a0 = *reinterpret_cast<const bf16x8*>(wsl + (size_t)c * INNER + quad * 8);
        bf16x8 a1 = *reinterpret_cast<const bf16x8*>(wsl + (size_t)c * INNER + 32 + quad * 8);
        #pragma unroll
        for (int dt = 0; dt < 4; dt++) {
            floatx4 d = {0.f, 0.f, 0.f, 0.f};
            d = __builtin_amdgcn_mfma_f32_16x16x32_bf16(b0[dt], a0, d, 0, 0, 0);
            d = __builtin_amdgcn_mfma_f32_16x16x32_bf16(b1[dt], a1, d, 0, 0, 0);
            short4 pk;
            pk.x = f2bs(d[0]); pk.y = f2bs(d[1]);
            pk.z = f2bs(d[2]); pk.w = f2bs(d[3]);
            *reinterpret_cast<short4*>(&w2[(size_t)c * 512 + dt * 16 + quad * 4]) = pk;
        }
    }
}

// ---------------------------------------------------------------------------
// Final segmented GEMM: out[row,:] = qn[row,:] @ W2T[bg]^T + b_out  (fp32 out)
// 2-phase double-buffer + launch_bounds(256,3); XCD-chunked swizzle.
// ---------------------------------------------------------------------------
__global__ __launch_bounds__(256, 3) void final_gemm_kernel(
        const __hip_bfloat16* __restrict__ qn, const __hip_bfloat16* __restrict__ w2t,
        const float* __restrict__ bias,
        const int* __restrict__ crow0, const int* __restrict__ crows,
        const int* __restrict__ cbg, const int* __restrict__ cnt,
        float* __restrict__ out) {
    __shared__ alignas(16) char smem2[32768];   // A0|B0|A1|B1
    int bid = xcd_swizzle(blockIdx.y * 4 + blockIdx.x, 4 * MAXCHUNK);
    const int chunk = bid >> 2;
    if (chunk >= *cnt) return;
    const int row0  = crow0[chunk];
    const int nrows = crows[chunk];
    const int bg    = cbg[chunk];
    const int col0 = (bid & 3) * 128;
    const int t = threadIdx.x;
    const int lane = t & 63;
    const int wave = t >> 6;
    const int wr = wave >> 1, wc = wave & 1;
    const int quad = lane >> 4, lr = lane & 15;

    floatx4 acc[4][4] = {};

    const int srow = t >> 2;
    const int scol = (((t & 3) ^ ((t >> 3) & 3))) * 8;
    const __hip_bfloat16* gA = qn + (size_t)(row0 + srow) * INNER + scol;
    const __hip_bfloat16* gB = w2t + (size_t)bg * 512 * 512 + (size_t)(col0 + srow) * 512 + scol;
    char* lA = smem2 + t * 16;
    char* lB = smem2 + 8192 + t * 16;

    gl_lds16(gA, lA);
    gl_lds16(gA + (size_t)64 * INNER, lA + 4096);
    gl_lds16(gB, lB);
    gl_lds16(gB + (size_t)64 * 512, lB + 4096);
    __syncthreads();

    for (int it = 0; it < INNER / 32; ++it) {
        const int cb = (it & 1) << 14;
        const int nb = cb ^ 16384;
        const int k1 = (it + 1) * 32;
        if (k1 < INNER) {
            gl_lds16(gA + k1, lA + nb);
            gl_lds16(gA + (size_t)64 * INNER + k1, lA + nb + 4096);
            gl_lds16(gB + k1, lB + nb);
            gl_lds16(gB + (size_t)64 * 512 + k1, lB + nb + 4096);
        }
        bf16x8 af[4], bf[4];
        #pragma unroll
        for (int mt = 0; mt < 4; mt++)
            af[mt] = frag_ld(smem2 + cb, wr * 64 + mt * 16 + lr, quad);
        #pragma unroll
        for (int nt = 0; nt < 4; nt++)
            bf[nt] = frag_ld(smem2 + cb + 8192, wc * 64 + nt * 16 + lr, quad);
        #pragma unroll
        for (int mt = 0; mt < 4; mt++)
            #pragma unroll
            for (int nt = 0; nt < 4; nt++)
                acc[mt][nt] = __builtin_amdgcn_mfma_f32_16x16x32_bf16(af[mt], bf[nt], acc[mt][nt], 0, 0, 0);
        __syncthreads();
    }

    #pragma unroll
    for (int nt = 0; nt < 4; nt++) {
        int col = col0 + wc * 64 + nt * 16 + lr;
        float bv = bias[col];
        #pragma unroll
        for (int mt = 0; mt < 4; mt++)
            #pragma unroll
            for (int reg = 0; reg < 4; reg++) {
                int rl = wr * 64 + mt * 16 + quad * 4 + reg;
                if (rl < nrows)
                    out[(size_t)(row0 + rl) * DIM + col] = acc[mt][nt][reg] + bv;
            }
    }
}

// ---------------------------------------------------------------------------
extern "C" void kernel_launch(void* const* d_in, const int* in_sizes, int n_in,
                              void* d_out, int out_size, void* d_ws, size_t ws_size,
                              hipStream_t stream) {
    const float* x     = (const float*)d_in[0];
    const float* w_qkv = (const float*)d_in[1];
    const float* ln1w  = (const float*)d_in[2];
    const float* ln1b  = (const float*)d_in[3];
    const float* ln2w  = (const float*)d_in[4];
    const float* ln2b  = (const float*)d_in[5];
    const float* w_out = (const float*)d_in[6];
    const float* b_out = (const float*)d_in[7];
    const int*   batch = (const int*)d_in[8];
    float* out = (float*)d_out;

    char* ws = (char*)d_ws;
    const size_t MB = 1u << 20;
    __hip_bfloat16* qn  = (__hip_bfloat16*)(ws);              // 64 MiB
    __hip_bfloat16* kb  = (__hip_bfloat16*)(ws + 64 * MB);    // 64 MiB [bh][d][n]
    __hip_bfloat16* vb  = (__hip_bfloat16*)(ws + 128 * MB);   // 64 MiB [bh][d][n]
    __hip_bfloat16* xb  = (__hip_bfloat16*)(ws + 192 * MB);   // xb then w2t
    __hip_bfloat16* w2t = (__hip_bfloat16*)(ws + 192 * MB);
    __hip_bfloat16* wb  = (__hip_bfloat16*)(ws + 256 * MB);   // 1.5 MiB
    __hip_bfloat16* wob = (__hip_bfloat16*)(ws + 258 * MB);   // 0.5 MiB
    char* meta = ws + 259 * MB;
    int*   starts = (int*)(meta);
    int*   sizes  = (int*)(meta + 128);
    float* inv    = (float*)(meta + 256);
    int*   crow0  = (int*)(meta + 512);
    int*   crows  = (int*)(meta + 512 + 4096);
    int*   cbg    = (int*)(meta + 512 + 8192);
    int*   cnt    = (int*)(meta + 512 + 12288);

    graph_info_kernel<<<1, 64, 0, stream>>>(batch, starts, sizes, inv,
                                            crow0, crows, cbg, cnt);
    convert3_kernel<<<16896, 256, 0, stream>>>(x, w_qkv, w_out, xb, wb, wob);
    qkv_gemm_kernel<<<dim3((3 * INNER) / 128, M_ROWS / 128), 256, 0, stream>>>(
        xb, wb, ln1w, ln1b, ln2w, ln2b, inv, batch, qn, kb, vb);
    ktv_w2_kernel<<<BATCH * HEADS * G, 256, 0, stream>>>(
        (const short*)kb, (const short*)vb, (const short*)wob, starts, sizes, (short*)w2t);
    final_gemm_kernel<<<dim3(4, MAXCHUNK), 256, 0, stream>>>(
        qn, w2t, b_out, crow0, crows, cbg, cnt, out);
}